// Round 2
// baseline (281.911 us; speedup 1.0000x reference)
//
#include <hip/hip_runtime.h>

#define NUM_LABELS 1025
#define NBIN (NUM_LABELS * 10)   // 10250 f32 = 41000 B of LDS per block
static constexpr int HW = 1024 * 1024;
static constexpr int NBATCH = 8;
static constexpr long long NPIX = (long long)NBATCH * HW;   // 8388608
static constexpr float LINE_THRESH = 63.75f;                 // 255/4
static constexpr int NSEG = NBATCH * NUM_LABELS;             // 8200

// Kernel 1: one pass. Each block serves EXACTLY ONE batch (grid partitioned
// by batch), so a label-only LDS histogram is unambiguous per (batch,label).
// Per-block LDS bins[lab*10 + j]:
//   j=0..3 : unmasked channel sums S_c
//   j=4    : unmasked count N
//   j=5..8 : wl==0 channel sums U_c   (T2_c = S_c - U_c)
//   j=9    : wl==0 count M            (T3   = N   - M)
// Also accumulates A = sum(wl * sum_c Is^2) as a per-block partial.
__global__ __launch_bounds__(512) void spx_k1(
    const float* __restrict__ Is, const int* __restrict__ Ispp,
    const float* __restrict__ Il, float* __restrict__ bins_g,
    float* __restrict__ a_g, int bpb)
{
    __shared__ float bins[NBIN];
    const int t = threadIdx.x;
    for (int i = t; i < NBIN; i += 512) bins[i] = 0.f;
    __syncthreads();

    const int b   = blockIdx.x / bpb;    // batch this block serves
    const int blk = blockIdx.x % bpb;    // index within the batch's blocks
    const long long planeI = (long long)b * HW;          // Ispp/Il plane base
    const long long chan0  = (long long)(b * 4) * HW;    // Is channel-0 base

    float a = 0.f;
    const int QB = HW >> 2;              // 262144 pixel-quads per batch
    for (int q = blk * 512 + t; q < QB; q += bpb * 512) {
        const int pix = q << 2;

        const int4   lab4 = *(const int4*)(Ispp + planeI + pix);
        const float4 il4  = *(const float4*)(Il + planeI + pix);
        float4 ch[4];
#pragma unroll
        for (int c = 0; c < 4; ++c)
            ch[c] = *(const float4*)(Is + chan0 + (long long)c * HW + pix);

        const int*   lab = (const int*)&lab4;
        const float* il  = (const float*)&il4;
        const float* f0  = (const float*)&ch[0];
        const float* f1  = (const float*)&ch[1];
        const float* f2  = (const float*)&ch[2];
        const float* f3  = (const float*)&ch[3];

#pragma unroll
        for (int j = 0; j < 4; ++j) {
            const float v0 = f0[j], v1 = f1[j], v2 = f2[j], v3 = f3[j];
            const int base = lab[j] * 10;
            atomicAdd(&bins[base + 0], v0);
            atomicAdd(&bins[base + 1], v1);
            atomicAdd(&bins[base + 2], v2);
            atomicAdd(&bins[base + 3], v3);
            atomicAdd(&bins[base + 4], 1.f);
            if (il[j] > LINE_THRESH) {
                a += v0 * v0 + v1 * v1 + v2 * v2 + v3 * v3;
            } else {
                atomicAdd(&bins[base + 5], v0);
                atomicAdd(&bins[base + 6], v1);
                atomicAdd(&bins[base + 7], v2);
                atomicAdd(&bins[base + 8], v3);
                atomicAdd(&bins[base + 9], 1.f);
            }
        }
    }
    __syncthreads();

    // flush this block's slice (coalesced)
    float* dst = bins_g + (size_t)blockIdx.x * NBIN;
    for (int i = t; i < NBIN; i += 512) dst[i] = bins[i];

    // deterministic block reduce of A
#pragma unroll
    for (int off = 32; off >= 1; off >>= 1) a += __shfl_xor(a, off, 64);
    __shared__ float apart[8];
    if ((t & 63) == 0) apart[t >> 6] = a;
    __syncthreads();
    if (t == 0) {
        float s = 0.f;
#pragma unroll
        for (int w = 0; w < 8; ++w) s += apart[w];
        a_g[blockIdx.x] = s;
    }
}

// Kernel 2: reduce the batch's slices per segment, per-segment correction:
//   corr_s = sum_c ( T3*mean_c^2 - 2*mean_c*T2_c ),  0 if label==0
__global__ __launch_bounds__(256) void spx_k2(
    const float* __restrict__ bins_g, int bpb, float* __restrict__ corr)
{
    const int lane = threadIdx.x & 63;
    const int s = blockIdx.x * 4 + (threadIdx.x >> 6);   // NSEG = 2050*4 exactly
    const int b   = s / NUM_LABELS;
    const int lab = s % NUM_LABELS;

    float v[10];
#pragma unroll
    for (int j = 0; j < 10; ++j) v[j] = 0.f;

    for (int k = lane; k < bpb; k += 64) {
        const float* p = bins_g + (size_t)(b * bpb + k) * NBIN + lab * 10;
#pragma unroll
        for (int j = 0; j < 5; ++j) {
            const float2 f = *(const float2*)(p + 2 * j);
            v[2 * j]     += f.x;
            v[2 * j + 1] += f.y;
        }
    }
#pragma unroll
    for (int off = 32; off >= 1; off >>= 1) {
#pragma unroll
        for (int j = 0; j < 10; ++j) v[j] += __shfl_xor(v[j], off, 64);
    }

    if (lane == 0) {
        float c = 0.f;
        if (lab != 0) {
            const float inv = 1.f / fmaxf(v[4], 1.f);
            const float t3  = v[4] - v[9];
#pragma unroll
            for (int j = 0; j < 4; ++j) {
                const float m  = v[j] * inv;
                const float t2 = v[j] - v[5 + j];
                c += t3 * m * m - 2.f * m * t2;
            }
        }
        corr[s] = c;
    }
}

// Kernel 3: deterministic final reduce: out = (sum(A partials) + sum(corr)) / NPIX
__global__ __launch_bounds__(1024) void spx_k3(
    const float* __restrict__ corr, const float* __restrict__ a_g, int SL,
    float* __restrict__ out)
{
    __shared__ float red[1024];
    float s = 0.f;
    for (int i = threadIdx.x; i < NSEG; i += 1024) s += corr[i];
    for (int i = threadIdx.x; i < SL;   i += 1024) s += a_g[i];
    red[threadIdx.x] = s;
    __syncthreads();
    for (int off = 512; off >= 1; off >>= 1) {
        if (threadIdx.x < (unsigned)off) red[threadIdx.x] += red[threadIdx.x + off];
        __syncthreads();
    }
    if (threadIdx.x == 0) out[0] = red[0] / 8388608.0f;
}

extern "C" void kernel_launch(void* const* d_in, const int* in_sizes, int n_in,
                              void* d_out, int out_size, void* d_ws, size_t ws_size,
                              hipStream_t stream)
{
    const float* Is   = (const float*)d_in[0];
    const int*   Ispp = (const int*)d_in[1];
    const float* Il   = (const float*)d_in[2];
    float* out = (float*)d_out;

    int SL = 512;                      // total K1 blocks; multiple of 8 (batches)
    while (SL > 8 &&
           ((size_t)SL * NBIN * 4 + (size_t)SL * 4 + (size_t)NSEG * 4) > ws_size)
        SL >>= 1;
    const int bpb = SL / NBATCH;       // blocks per batch

    float* bins_g = (float*)d_ws;
    float* a_g    = bins_g + (size_t)SL * NBIN;
    float* corr   = a_g + SL;

    spx_k1<<<SL, 512, 0, stream>>>(Is, Ispp, Il, bins_g, a_g, bpb);
    spx_k2<<<NSEG / 4, 256, 0, stream>>>(bins_g, bpb, corr);
    spx_k3<<<1, 1024, 0, stream>>>(corr, a_g, SL, out);
}

// Round 3
// 55.798 us; speedup vs baseline: 5.0523x; 5.0523x over previous
//
#include <hip/hip_runtime.h>

#define NUM_LABELS 1025
#define STRIDE 9                          // dwords per label group; gcd(9,32)=1 spreads banks
#define NBIN (NUM_LABELS * STRIDE)        // 9225 dwords = 36.9 KB LDS
static constexpr int HW = 1024 * 1024;
static constexpr int NBATCH = 8;
static constexpr float LINE_THRESH = 63.75f;   // 255/4
static constexpr int NSEG = NBATCH * NUM_LABELS;  // 8200
static constexpr float QSCALE = 16384.0f;      // 2^14 fixed point
static constexpr float INVQ   = 1.0f / 16384.0f;
// count embedded at bit 24 of the c0 bin: v = cnt<<24 + sum(x0*2^14), |sum| < 2^23

// K1: one pass. Each block serves ONE batch. LDS int histogram, label-only key.
//   bins[lab*9 + 0..3] : unmasked fixed-point channel sums; +0 embeds count<<24
//   bins[lab*9 + 4..7] : wl==0 (complement) sums;           +4 embeds mcount<<24
// Registers: a = sum over wl==1 pixels of sum_c x^2 (f32, deterministic reduce).
__global__ __launch_bounds__(512) void spx_k1(
    const float* __restrict__ Is, const int* __restrict__ Ispp,
    const float* __restrict__ Il, int* __restrict__ bins_g,
    float* __restrict__ a_g, int bpb)
{
    __shared__ int bins[NBIN];
    const int t = threadIdx.x;
    for (int i = t; i < NBIN; i += 512) bins[i] = 0;
    __syncthreads();

    const int b   = blockIdx.x / bpb;
    const int blk = blockIdx.x % bpb;
    const long long planeI = (long long)b * HW;
    const long long chan0  = (long long)(b * 4) * HW;

    float a = 0.f;
    const int QB = HW >> 2;                    // 262144 quads per batch
    for (int q = blk * 512 + t; q < QB; q += bpb * 512) {
        const int pix = q << 2;

        const int4   lab4 = *(const int4*)(Ispp + planeI + pix);
        const float4 il4  = *(const float4*)(Il + planeI + pix);
        float4 ch[4];
#pragma unroll
        for (int c = 0; c < 4; ++c)
            ch[c] = *(const float4*)(Is + chan0 + (long long)c * HW + pix);

        const int*   lab = (const int*)&lab4;
        const float* il  = (const float*)&il4;
        const float* f0  = (const float*)&ch[0];
        const float* f1  = (const float*)&ch[1];
        const float* f2  = (const float*)&ch[2];
        const float* f3  = (const float*)&ch[3];

#pragma unroll
        for (int j = 0; j < 4; ++j) {
            const float v0 = f0[j], v1 = f1[j], v2 = f2[j], v3 = f3[j];
            const int base = lab[j] * STRIDE;
            const int q0 = __float2int_rn(v0 * QSCALE) + (1 << 24);
            const int q1 = __float2int_rn(v1 * QSCALE);
            const int q2 = __float2int_rn(v2 * QSCALE);
            const int q3 = __float2int_rn(v3 * QSCALE);
            atomicAdd(&bins[base + 0], q0);
            atomicAdd(&bins[base + 1], q1);
            atomicAdd(&bins[base + 2], q2);
            atomicAdd(&bins[base + 3], q3);
            if (il[j] > LINE_THRESH) {
                a += v0 * v0 + v1 * v1 + v2 * v2 + v3 * v3;
            } else {
                atomicAdd(&bins[base + 4], q0);
                atomicAdd(&bins[base + 5], q1);
                atomicAdd(&bins[base + 6], q2);
                atomicAdd(&bins[base + 7], q3);
            }
        }
    }
    __syncthreads();

    int* dst = bins_g + (size_t)blockIdx.x * NBIN;
    for (int i = t; i < NBIN; i += 512) dst[i] = bins[i];

#pragma unroll
    for (int off = 32; off >= 1; off >>= 1) a += __shfl_xor(a, off, 64);
    __shared__ float apart[8];
    if ((t & 63) == 0) apart[t >> 6] = a;
    __syncthreads();
    if (t == 0) {
        float s = 0.f;
#pragma unroll
        for (int w = 0; w < 8; ++w) s += apart[w];
        a_g[blockIdx.x] = s;
    }
}

// K2: per segment, decode+reduce the batch's slices, emit correction:
//   corr_s = sum_c ( T3*m_c^2 - 2*m_c*T2_c ),  m = S/N, T2 = S-U, T3 = N-M
__global__ __launch_bounds__(256) void spx_k2(
    const int* __restrict__ bins_g, int bpb, float* __restrict__ corr)
{
    const int lane = threadIdx.x & 63;
    const int s = blockIdx.x * 4 + (threadIdx.x >> 6);   // NSEG = 2050*4
    const int b   = s / NUM_LABELS;
    const int lab = s % NUM_LABELS;

    // v: S0..S3, N, U0..U3, M  (f32 accumulators)
    float v[10];
#pragma unroll
    for (int j = 0; j < 10; ++j) v[j] = 0.f;

    for (int k = lane; k < bpb; k += 64) {
        const int* p = bins_g + (size_t)(b * bpb + k) * NBIN + lab * STRIDE;
        int w[8];
#pragma unroll
        for (int j = 0; j < 8; ++j) w[j] = p[j];

        const unsigned cN = ((unsigned)(w[0] + (1 << 23))) >> 24;
        const int      s0 = w[0] - (int)(cN << 24);
        const unsigned cM = ((unsigned)(w[4] + (1 << 23))) >> 24;
        const int      u0 = w[4] - (int)(cM << 24);

        v[0] += (float)s0 * INVQ;
        v[1] += (float)w[1] * INVQ;
        v[2] += (float)w[2] * INVQ;
        v[3] += (float)w[3] * INVQ;
        v[4] += (float)cN;
        v[5] += (float)u0 * INVQ;
        v[6] += (float)w[5] * INVQ;
        v[7] += (float)w[6] * INVQ;
        v[8] += (float)w[7] * INVQ;
        v[9] += (float)cM;
    }
#pragma unroll
    for (int off = 32; off >= 1; off >>= 1) {
#pragma unroll
        for (int j = 0; j < 10; ++j) v[j] += __shfl_xor(v[j], off, 64);
    }

    if (lane == 0) {
        float c = 0.f;
        if (lab != 0) {
            const float inv = 1.f / fmaxf(v[4], 1.f);
            const float t3  = v[4] - v[9];
#pragma unroll
            for (int j = 0; j < 4; ++j) {
                const float m  = v[j] * inv;
                const float t2 = v[j] - v[5 + j];
                c += t3 * m * m - 2.f * m * t2;
            }
        }
        corr[s] = c;
    }
}

// K3: out = (sum(A partials) + sum(corr)) / NPIX, deterministic
__global__ __launch_bounds__(1024) void spx_k3(
    const float* __restrict__ corr, const float* __restrict__ a_g, int SL,
    float* __restrict__ out)
{
    __shared__ float red[1024];
    float s = 0.f;
    for (int i = threadIdx.x; i < NSEG; i += 1024) s += corr[i];
    for (int i = threadIdx.x; i < SL;   i += 1024) s += a_g[i];
    red[threadIdx.x] = s;
    __syncthreads();
    for (int off = 512; off >= 1; off >>= 1) {
        if (threadIdx.x < (unsigned)off) red[threadIdx.x] += red[threadIdx.x + off];
        __syncthreads();
    }
    if (threadIdx.x == 0) out[0] = red[0] / 8388608.0f;
}

extern "C" void kernel_launch(void* const* d_in, const int* in_sizes, int n_in,
                              void* d_out, int out_size, void* d_ws, size_t ws_size,
                              hipStream_t stream)
{
    const float* Is   = (const float*)d_in[0];
    const int*   Ispp = (const int*)d_in[1];
    const float* Il   = (const float*)d_in[2];
    float* out = (float*)d_out;

    int SL = 512;                      // K1 blocks; multiple of 8 batches
    while (SL > 8 &&
           ((size_t)SL * NBIN * 4 + (size_t)SL * 4 + (size_t)NSEG * 4) > ws_size)
        SL >>= 1;
    const int bpb = SL / NBATCH;

    int*   bins_g = (int*)d_ws;
    float* a_g    = (float*)(bins_g + (size_t)SL * NBIN);
    float* corr   = a_g + SL;

    spx_k1<<<SL, 512, 0, stream>>>(Is, Ispp, Il, bins_g, a_g, bpb);
    spx_k2<<<NSEG / 4, 256, 0, stream>>>(bins_g, bpb, corr);
    spx_k3<<<1, 1024, 0, stream>>>(corr, a_g, SL, out);
}